// Round 9
// baseline (191.427 us; speedup 1.0000x reference)
//
#include <hip/hip_runtime.h>
#include <math.h>

typedef __bf16 bf16;
typedef __attribute__((ext_vector_type(4))) __bf16 bf16x4;
typedef __attribute__((ext_vector_type(8))) __bf16 bf16x8;
typedef __attribute__((ext_vector_type(4))) float f32x4;

#define B_SZ 2
#define T_SZ 1024
#define DM_SZ 1024
#define H_SZ 16
#define D_SZ 64
#define L_SZ 12
#define M_ROWS 2048      // B*T
#define N_PAD 3328       // q(1024)+k(1024)+v(1024)+logit(192)+pad(64)

__device__ __forceinline__ f32x4 mfma_16x16x32(bf16x8 a, bf16x8 b, f32x4 c) {
  return __builtin_amdgcn_mfma_f32_16x16x32_bf16(a, b, c, 0, 0, 0);
}

// async global->LDS, 16B/lane; LDS dest = wave-uniform base + lane*16.
__device__ __forceinline__ void gload_lds16(const bf16* g, bf16* l) {
  __builtin_amdgcn_global_load_lds((const __attribute__((address_space(1))) void*)g,
                                   (__attribute__((address_space(3))) void*)l,
                                   16, 0, 0);
}

// ---------------------------------------------------------------------------
// Prep (1328 blocks): [0,1024) qw/kw/vw/ow transpose tiles, [1024,1072) lw,
// [1072,1328) x fp32->bf16 cast units.
// ---------------------------------------------------------------------------
__global__ __launch_bounds__(256) void k_prep(
    const float* __restrict__ x, bf16* __restrict__ xb,
    const float* __restrict__ qw, const float* __restrict__ kw,
    const float* __restrict__ vw, const float* __restrict__ ow,
    const float* __restrict__ lw,
    bf16* __restrict__ wqkvT, bf16* __restrict__ owT) {
  const int u = blockIdx.x;
  const int t = threadIdx.x;
  if (u >= 1072) {  // cast
    const size_t base = (size_t)(u - 1072) * 8192 + t * 32;
#pragma unroll
    for (int c = 0; c < 4; ++c) {
      const float* p = x + base + c * 8;
      f32x4 a = *(const f32x4*)p;
      f32x4 b = *(const f32x4*)(p + 4);
      bf16x8 o;
#pragma unroll
      for (int e = 0; e < 4; ++e) { o[e] = (bf16)a[e]; o[e + 4] = (bf16)b[e]; }
      *(bf16x8*)(xb + base + c * 8) = o;
    }
    return;
  }
  __shared__ __align__(16) bf16 tile[64][66];
  const float* in; bf16* out; int C = 1024, tx, ty;
  if (u < 1024) {
    const int z = u >> 8, id = u & 255;
    tx = id & 15; ty = id >> 4;
    if (z == 0)      { in = qw; out = wqkvT; }
    else if (z == 1) { in = kw; out = wqkvT + (size_t)1024 * DM_SZ; }
    else if (z == 2) { in = vw; out = wqkvT + (size_t)2048 * DM_SZ; }
    else             { in = ow; out = owT; }
  } else {
    const int id = u - 1024;
    tx = id % 3; ty = id / 3;
    in = lw; out = wqkvT + (size_t)3072 * DM_SZ; C = 192;
  }
  const int tc = tx * 64, tr = ty * 64;
  const int r = t >> 2;
  const int c4 = (t & 3) << 4;
  const float* src = in + (size_t)(tr + r) * C + tc + c4;
  f32x4 f0 = *(const f32x4*)(src);
  f32x4 f1 = *(const f32x4*)(src + 4);
  f32x4 f2 = *(const f32x4*)(src + 8);
  f32x4 f3 = *(const f32x4*)(src + 12);
#pragma unroll
  for (int e = 0; e < 4; ++e) {
    tile[r][c4 + e]      = (bf16)f0[e];
    tile[r][c4 + 4 + e]  = (bf16)f1[e];
    tile[r][c4 + 8 + e]  = (bf16)f2[e];
    tile[r][c4 + 12 + e] = (bf16)f3[e];
  }
  __syncthreads();
  bf16x8 w0, w1;
#pragma unroll
  for (int e = 0; e < 8; ++e) { w0[e] = tile[c4 + e][r]; w1[e] = tile[c4 + 8 + e][r]; }
  bf16* dst = out + (size_t)(tc + r) * DM_SZ + tr + c4;
  *(bf16x8*)(dst) = w0;
  *(bf16x8*)(dst + 8) = w1;
}

// ---------------------------------------------------------------------------
// Fused QKVL GEMM: 128(M) x 64(N) tiles, BK=64, grid (52,16).
// seg0: phi->Qp.  seg1: phi->Kp AND transposed KTg AND per-tile K1 sums.
// seg2: V transposed -> VTg.  seg3: f32 logits.
// ---------------------------------------------------------------------------
__global__ __launch_bounds__(256) void k_gemm_qkvl(
    const bf16* __restrict__ A, const bf16* __restrict__ Wt,
    const float* __restrict__ qb, const float* __restrict__ kb,
    const float* __restrict__ vb, const float* __restrict__ lb,
    bf16* __restrict__ Qp, bf16* __restrict__ Kp, bf16* __restrict__ KTg,
    bf16* __restrict__ VTg, float* __restrict__ K1g, float* __restrict__ logit) {
  __shared__ __align__(16) char smem[24576];  // As 16KB + Bs 8KB / Trt 17.4KB
  bf16* As = (bf16*)smem;
  bf16* Bs = As + 8192;
  const int nb = blockIdx.x * 64;
  const int mb = blockIdx.y * 128;
  const int t = threadIdx.x;
  const int wv = t >> 6;
  const int lane = t & 63;
  const int l16 = lane & 15;
  const int quad = lane >> 4;
  const int wm = wv * 32;
  const int trow = t >> 3;        // 0..31
  const int tcol = (t & 7) * 8;

  const f32x4 zero4 = {0.f, 0.f, 0.f, 0.f};
  f32x4 acc[2][4];
#pragma unroll
  for (int i = 0; i < 2; ++i)
#pragma unroll
    for (int j = 0; j < 4; ++j) acc[i][j] = zero4;

  const bf16* ag = A + (size_t)(mb + trow) * DM_SZ + tcol;
  const bf16* bg = Wt + (size_t)(nb + trow) * DM_SZ + tcol;

  for (int k0 = 0; k0 < DM_SZ; k0 += 64) {
    __syncthreads();
#pragma unroll
    for (int i = 0; i < 4; ++i)
      gload_lds16(ag + (size_t)i * 32 * DM_SZ + k0, As + i * 2048 + t * 8);
#pragma unroll
    for (int i = 0; i < 2; ++i)
      gload_lds16(bg + (size_t)i * 32 * DM_SZ + k0, Bs + i * 2048 + t * 8);
    __syncthreads();
#pragma unroll
    for (int ks = 0; ks < 2; ++ks) {
      bf16x8 af0 = *(const bf16x8*)(As + (wm + l16) * 64 + ks * 32 + quad * 8);
      bf16x8 af1 = *(const bf16x8*)(As + (wm + 16 + l16) * 64 + ks * 32 + quad * 8);
#pragma unroll
      for (int ni = 0; ni < 4; ++ni) {
        bf16x8 bfr = *(const bf16x8*)(Bs + (ni * 16 + l16) * 64 + ks * 32 + quad * 8);
        acc[0][ni] = mfma_16x16x32(af0, bfr, acc[0][ni]);
        acc[1][ni] = mfma_16x16x32(af1, bfr, acc[1][ni]);
      }
    }
  }

  const int seg = nb >> 10;  // 0=q 1=k 2=v 3=logit/pad
  if (seg == 0) {
    const int c0 = nb & 1023;
#pragma unroll
    for (int ni = 0; ni < 4; ++ni) {
      const int col = c0 + ni * 16 + l16;
      const float bv = qb[col];
#pragma unroll
      for (int mi = 0; mi < 2; ++mi) {
#pragma unroll
        for (int r = 0; r < 4; ++r) {
          const int row = mb + wm + mi * 16 + quad * 4 + r;
          float v = acc[mi][ni][r] + bv;
          v = (v > 0.f) ? (v + 1.f) : __expf(v);
          Qp[(size_t)row * DM_SZ + col] = (bf16)v;
        }
      }
    }
  } else if (seg == 1) {
    // K: phi -> Kp (normal), plus transpose -> KTg, plus per-tile K1 sums
    bf16* Trt = (bf16*)smem;
    const int c0 = nb - 1024;          // h*64
    const int h = c0 >> 6;
    const int bq = mb >> 10;
    const int m0g = mb & 1023;
    const int bh = bq * 16 + h;
    __syncthreads();  // K-loop LDS frag reads complete before Trt overwrite
#pragma unroll
    for (int ni = 0; ni < 4; ++ni) {
      const int nloc = ni * 16 + l16;
      const float bv = kb[c0 + nloc];
#pragma unroll
      for (int mi = 0; mi < 2; ++mi) {
        const int mloc = wm + mi * 16 + quad * 4;
        bf16x4 pk;
#pragma unroll
        for (int r = 0; r < 4; ++r) {
          float v = acc[mi][ni][r] + bv;
          v = (v > 0.f) ? (v + 1.f) : __expf(v);
          pk[r] = (bf16)v;
          Kp[(size_t)(mb + mloc + r) * DM_SZ + c0 + nloc] = (bf16)v;
        }
        *(bf16x4*)&Trt[nloc * 136 + mloc] = pk;
      }
    }
    __syncthreads();
    {
      const int dn = t >> 2, ch = t & 3;   // 64 d-rows x 4 chunks of 32 cols
      bf16* dst = KTg + ((size_t)(bh * 64 + dn)) * T_SZ + m0g + ch * 32;
      const bf16* srcl = Trt + dn * 136 + ch * 32;
      *(bf16x8*)(dst) = *(const bf16x8*)(srcl);
      *(bf16x8*)(dst + 8) = *(const bf16x8*)(srcl + 8);
      *(bf16x8*)(dst + 16) = *(const bf16x8*)(srcl + 16);
      *(bf16x8*)(dst + 24) = *(const bf16x8*)(srcl + 24);
    }
    if (t < 128) {  // K1[bh][jt][d] = sum_t phiK
      const int d = t >> 1, half = t & 1;
      const bf16* rowp = Trt + d * 136 + half * 64;
      float s = 0.f;
#pragma unroll
      for (int e = 0; e < 64; ++e) s += (float)rowp[e];
      K1g[((size_t)bh * 16 + (m0g >> 6) + half) * 64 + d] = s;
    }
  } else if (seg == 2) {
    // V: bias, transpose via LDS, write VTg[bh*64+d][t]
    bf16* Trt = (bf16*)smem;
    const int cb = nb - 2048;
    __syncthreads();
#pragma unroll
    for (int ni = 0; ni < 4; ++ni) {
      const int nloc = ni * 16 + l16;
      const float bv = vb[cb + nloc];
#pragma unroll
      for (int mi = 0; mi < 2; ++mi) {
        const int mloc = wm + mi * 16 + quad * 4;
        bf16x4 pk;
#pragma unroll
        for (int r = 0; r < 4; ++r) pk[r] = (bf16)(acc[mi][ni][r] + bv);
        *(bf16x4*)&Trt[nloc * 136 + mloc] = pk;
      }
    }
    __syncthreads();
    const int dn = t >> 2, ch = t & 3;
    const int bq = mb >> 10;
    const int m0g = mb & 1023;
    bf16* dst = VTg + ((size_t)(bq * 1024 + cb + dn)) * T_SZ + m0g + ch * 32;
    const bf16* srcl = Trt + dn * 136 + ch * 32;
    *(bf16x8*)(dst) = *(const bf16x8*)(srcl);
    *(bf16x8*)(dst + 8) = *(const bf16x8*)(srcl + 8);
    *(bf16x8*)(dst + 16) = *(const bf16x8*)(srcl + 16);
    *(bf16x8*)(dst + 24) = *(const bf16x8*)(srcl + 24);
  } else {
    const int lc0 = nb - 3072;
#pragma unroll
    for (int ni = 0; ni < 4; ++ni) {
      const int lcol = lc0 + ni * 16 + l16;
      if (lcol < H_SZ * L_SZ) {
        const float bv = lb[lcol];
#pragma unroll
        for (int mi = 0; mi < 2; ++mi) {
#pragma unroll
          for (int r = 0; r < 4; ++r) {
            const int row = mb + wm + mi * 16 + quad * 4 + r;
            logit[(size_t)row * (H_SZ * L_SZ) + lcol] = acc[mi][ni][r] + bv;
          }
        }
      }
    }
  }
}

// ---------------------------------------------------------------------------
// Chunked Fenwick attention (O(T log T)) + fused softmax-12.
// Off-diag tiles grouped by dyadic ranges [pfx, pfx+2^b) for set bits b of it:
//   M_b = V^T phiK over range (long MFMA), G_b = phiQ M_b^T, scaled per row by
//   w[6+b] (rows 0-62) / w[6+fls((it+1)^pfx)] (row 63 — coarser partition).
// den via per-tile K1 vectors. Diagonal tile exact per element.
// ---------------------------------------------------------------------------
__global__ __launch_bounds__(256) void k_attn(const bf16* __restrict__ Qp,
                                              const bf16* __restrict__ Kp,
                                              const bf16* __restrict__ KTg,
                                              const bf16* __restrict__ VTg,
                                              const float* __restrict__ K1g,
                                              const float* __restrict__ Lg,
                                              bf16* __restrict__ O) {
  __shared__ float Ws[64 * L_SZ];
  __shared__ __align__(16) bf16 Mlds[64 * 72];
  __shared__ float K1Lds[64];
  __shared__ __align__(16) bf16 Pl[4][16][80];

  const int idx = blockIdx.x;
  const int s = idx >> 5;
  const int bh = idx & 31;
  const int it = (s < 8) ? (15 - s) : (s - 8);  // heavy-first balance
  const int b_ = bh >> 4;
  const int h = bh & 15;
  const int i0 = it * 64;
  const int t = threadIdx.x;
  const int wv = t >> 6;
  const int lane = t & 63;
  const int l16 = lane & 15;
  const int quad = lane >> 4;
  const int m0 = wv * 16;

  const size_t base_bt = (size_t)b_ * T_SZ;

  const bf16* qptr = Qp + (base_bt + i0 + m0 + l16) * DM_SZ + h * 64 + quad * 8;
  const bf16x8 aq0 = *(const bf16x8*)(qptr);
  const bf16x8 aq1 = *(const bf16x8*)(qptr + 32);

  if (t < 64) {  // fused softmax for this block's 64 query rows
    const float* lp = Lg + (base_bt + i0 + t) * (H_SZ * L_SZ) + h * L_SZ;
    float v[L_SZ];
    float m = -1e30f;
#pragma unroll
    for (int l = 0; l < L_SZ; ++l) { v[l] = lp[l]; m = fmaxf(m, v[l]); }
    float sum = 0.f;
#pragma unroll
    for (int l = 0; l < L_SZ; ++l) { v[l] = __expf(v[l] - m); sum += v[l]; }
    const float inv = 1.f / sum;
#pragma unroll
    for (int l = 0; l < L_SZ; ++l) Ws[t * L_SZ + l] = v[l] * inv;
  }
  __syncthreads();

  const f32x4 zero4 = {0.f, 0.f, 0.f, 0.f};
  f32x4 accn[4];
#pragma unroll
  for (int tn = 0; tn < 4; ++tn) accn[tn] = zero4;
  float den_a = 0.f;     // per-lane (A-layout row m0+l16) group den
  float dden[4] = {0.f, 0.f, 0.f, 0.f};  // diag den (C-layout)

  const int il_base = m0 + quad * 4;
  const bf16* c1a = VTg + ((size_t)(bh * 64 + m0 + l16)) * T_SZ;
  const bf16* c1b = KTg + ((size_t)(bh * 64)) * T_SZ;

  // ---- off-diagonal groups ----
#pragma unroll
  for (int b = 3; b >= 0; --b) {
    if (!(it & (1 << b))) continue;
    const int pfx = (it >> (b + 1)) << (b + 1);
    const int hi = pfx + (1 << b);
    // C1: M = sum over range of V^T phiK  (m=d2 rows, n=d1 cols, k=j)
    f32x4 macc[4];
#pragma unroll
    for (int ni = 0; ni < 4; ++ni) macc[ni] = zero4;
    for (int kt = pfx; kt < hi; ++kt) {
      const int k0 = kt * 64;
      bf16x8 a0 = *(const bf16x8*)(c1a + k0 + quad * 8);
      bf16x8 a1 = *(const bf16x8*)(c1a + k0 + 32 + quad * 8);
#pragma unroll
      for (int ni = 0; ni < 4; ++ni) {
        const bf16* brow = c1b + (size_t)(ni * 16 + l16) * T_SZ + k0;
        bf16x8 b0 = *(const bf16x8*)(brow + quad * 8);
        bf16x8 b1 = *(const bf16x8*)(brow + 32 + quad * 8);
        macc[ni] = mfma_16x16x32(a0, b0, macc[ni]);
        macc[ni] = mfma_16x16x32(a1, b1, macc[ni]);
      }
    }
    __syncthreads();  // previous group's Mlds/K1Lds reads complete
#pragma unroll
    for (int ni = 0; ni < 4; ++ni) {
#pragma unroll
      for (int r = 0; r < 4; ++r)
        Mlds[(m0 + quad * 4 + r) * 72 + ni * 16 + l16] = (bf16)macc[ni][r];
    }
    if (t < 64) {
      float ssum = 0.f;
      for (int kt = pfx; kt < hi; ++kt)
        ssum += K1g[((size_t)bh * 16 + kt) * 64 + t];
      K1Lds[t] = ssum;
    }
    __syncthreads();
    // C2: tmp = phiQ @ M^T
    f32x4 tmp[4];
#pragma unroll
    for (int ni = 0; ni < 4; ++ni) tmp[ni] = zero4;
#pragma unroll
    for (int ks = 0; ks < 2; ++ks) {
      const bf16x8 aqk = ks ? aq1 : aq0;
#pragma unroll
      for (int ni = 0; ni < 4; ++ni) {
        bf16x8 bm = *(const bf16x8*)(Mlds + (ni * 16 + l16) * 72 + ks * 32 + quad * 8);
        tmp[ni] = mfma_16x16x32(aqk, bm, tmp[ni]);
      }
    }
    const int lvlA = 6 + b;
    const int lvlB = 6 + (31 - __clz((unsigned)((it + 1) ^ pfx)));
    float wrow[4];
#pragma unroll
    for (int r = 0; r < 4; ++r) {
      const int il = il_base + r;
      wrow[r] = Ws[il * L_SZ + ((il == 63) ? lvlB : lvlA)];
    }
#pragma unroll
    for (int ni = 0; ni < 4; ++ni)
#pragma unroll
      for (int r = 0; r < 4; ++r) accn[ni][r] += wrow[r] * tmp[ni][r];
    // den: dot(phiq_row, K1L) per A-layout row
    {
      const int ilA = m0 + l16;
      const float wA = Ws[ilA * L_SZ + ((ilA == 63) ? lvlB : lvlA)];
      float dot = 0.f;
#pragma unroll
      for (int e = 0; e < 8; ++e)
        dot += (float)aq0[e] * K1Lds[quad * 8 + e] +
               (float)aq1[e] * K1Lds[32 + quad * 8 + e];
      dot += __shfl_xor(dot, 16, 64);
      dot += __shfl_xor(dot, 32, 64);
      den_a += wA * dot;
    }
  }

  // ---- diagonal tile: exact per-element level + causal mask ----
  {
    const int j0 = i0;
    f32x4 sacc[4];
#pragma unroll
    for (int tn = 0; tn < 4; ++tn) sacc[tn] = zero4;
#pragma unroll
    for (int ks = 0; ks < 2; ++ks) {
      const bf16x8 aqk = ks ? aq1 : aq0;
#pragma unroll
      for (int tn = 0; tn < 4; ++tn) {
        bf16x8 bk = *(const bf16x8*)(Kp + (base_bt + j0 + tn * 16 + l16) * DM_SZ +
                                     h * 64 + ks * 32 + quad * 8);
        sacc[tn] = mfma_16x16x32(aqk, bk, sacc[tn]);
      }
    }
#pragma unroll
    for (int tn = 0; tn < 4; ++tn) {
#pragma unroll
      for (int r = 0; r < 4; ++r) {
        const int il = il_base + r;
        const int ig = i0 + il;
        const int jg = j0 + tn * 16 + l16;
        float p = 0.f;
        if (jg <= ig) {
          const int lvl = 31 - __clz((unsigned)((ig + 1) ^ jg));
          p = sacc[tn][r] * Ws[il * L_SZ + lvl];
        }
        dden[r] += p;
        Pl[wv][quad * 4 + r][(tn * 16 + l16) ^ (quad << 4)] = (bf16)p;
      }
    }
    // PV: A = P (LDS round-trip), B = V^T rows direct from global
#pragma unroll
    for (int ks = 0; ks < 2; ++ks) {
      bf16x8 apf = *(const bf16x8*)&Pl[wv][l16][(ks * 32 + quad * 8) ^ ((l16 >> 2) << 4)];
#pragma unroll
      for (int tn = 0; tn < 4; ++tn) {
        bf16x8 bvf = *(const bf16x8*)(VTg + ((size_t)(bh * 64 + tn * 16 + l16)) * T_SZ +
                                      j0 + ks * 32 + quad * 8);
        accn[tn] = mfma_16x16x32(apf, bvf, accn[tn]);
      }
    }
  }

  // ---- final den: diag xor-reduce + group shuffle to C-layout ----
#pragma unroll
  for (int r = 0; r < 4; ++r) {
    float d = dden[r];
    d += __shfl_xor(d, 1, 64);
    d += __shfl_xor(d, 2, 64);
    d += __shfl_xor(d, 4, 64);
    d += __shfl_xor(d, 8, 64);
    const float dg = __shfl(den_a, quad * 4 + r, 64);  // den_a uniform over quads
    dden[r] = fmaxf(d + dg, 1e-6f);
  }

#pragma unroll
  for (int tn = 0; tn < 4; ++tn) {
#pragma unroll
    for (int r = 0; r < 4; ++r) {
      const int il = il_base + r;
      O[(base_bt + i0 + il) * DM_SZ + h * 64 + tn * 16 + l16] =
          (bf16)(accn[tn][r] / dden[r]);
    }
  }
}

// ---------------------------------------------------------------------------
// Output GEMM: attn(2048x1024) x owT(1024x1024) + ob -> f32 out.
// Tile 64x64, grid 512, global_load_lds staging.
// ---------------------------------------------------------------------------
__global__ __launch_bounds__(256) void k_gemm_out(const bf16* __restrict__ A,
                                                  const bf16* __restrict__ Wt,
                                                  const float* __restrict__ ob,
                                                  float* __restrict__ out) {
  __shared__ __align__(16) bf16 As[64 * 64];
  __shared__ __align__(16) bf16 Bs[64 * 64];
  const int nb = (blockIdx.x & 15) * 64;
  const int mb = (blockIdx.x >> 4) * 64;
  const int t = threadIdx.x;
  const int wv = t >> 6;
  const int lane = t & 63;
  const int l16 = lane & 15;
  const int quad = lane >> 4;
  const int wm = wv * 16;
  const int trow = t >> 3;
  const int tcol = (t & 7) * 8;

  const f32x4 zero4 = {0.f, 0.f, 0.f, 0.f};
  f32x4 acc[4];
#pragma unroll
  for (int j = 0; j < 4; ++j) acc[j] = zero4;

  const bf16* ag = A + (size_t)(mb + trow) * DM_SZ + tcol;
  const bf16* bg = Wt + (size_t)(nb + trow) * DM_SZ + tcol;

  for (int k0 = 0; k0 < DM_SZ; k0 += 64) {
    __syncthreads();
    gload_lds16(ag + k0, As + t * 8);
    gload_lds16(ag + (size_t)32 * DM_SZ + k0, As + 2048 + t * 8);
    gload_lds16(bg + k0, Bs + t * 8);
    gload_lds16(bg + (size_t)32 * DM_SZ + k0, Bs + 2048 + t * 8);
    __syncthreads();
#pragma unroll
    for (int ks = 0; ks < 2; ++ks) {
      bf16x8 af = *(const bf16x8*)(As + (wm + l16) * 64 + ks * 32 + quad * 8);
#pragma unroll
      for (int ni = 0; ni < 4; ++ni) {
        bf16x8 bfr = *(const bf16x8*)(Bs + (ni * 16 + l16) * 64 + ks * 32 + quad * 8);
        acc[ni] = mfma_16x16x32(af, bfr, acc[ni]);
      }
    }
  }
#pragma unroll
  for (int ni = 0; ni < 4; ++ni) {
    const int col = nb + ni * 16 + l16;
    const float bv = ob[col];
#pragma unroll
    for (int r = 0; r < 4; ++r) {
      const int row = mb + wm + quad * 4 + r;
      out[(size_t)row * DM_SZ + col] = acc[ni][r] + bv;
    }
  }
}

// ---------------------------------------------------------------------------
extern "C" void kernel_launch(void* const* d_in, const int* in_sizes, int n_in,
                              void* d_out, int out_size, void* d_ws, size_t ws_size,
                              hipStream_t stream) {
  (void)in_sizes; (void)n_in; (void)out_size; (void)ws_size;
  const float* x  = (const float*)d_in[0];
  const float* qw = (const float*)d_in[1];
  const float* qb = (const float*)d_in[2];
  const float* kw = (const float*)d_in[3];
  const float* kb = (const float*)d_in[4];
  const float* vw = (const float*)d_in[5];
  const float* vb = (const float*)d_in[6];
  const float* lw = (const float*)d_in[7];
  const float* lb = (const float*)d_in[8];
  const float* ow = (const float*)d_in[9];
  const float* ob = (const float*)d_in[10];
  // d_in[11] = level_masks: unused — lvl(i,j) = 31 - clz((i+1)^j).

  char* ws = (char*)d_ws;
  size_t off = 0;
  auto alloc = [&](size_t bytes) -> char* {
    char* p = ws + off;
    off += (bytes + 255) & ~(size_t)255;
    return p;
  };
  bf16* xb     = (bf16*)alloc((size_t)M_ROWS * DM_SZ * 2);
  bf16* wqkvT  = (bf16*)alloc((size_t)N_PAD * DM_SZ * 2);  // rows 3264..3327 garbage (harmless)
  bf16* owT    = (bf16*)alloc((size_t)DM_SZ * DM_SZ * 2);
  bf16* Qp     = (bf16*)alloc((size_t)M_ROWS * DM_SZ * 2);
  bf16* Kpb    = (bf16*)alloc((size_t)M_ROWS * DM_SZ * 2);
  bf16* KTg    = (bf16*)alloc((size_t)M_ROWS * DM_SZ * 2);
  bf16* VTg    = (bf16*)alloc((size_t)M_ROWS * DM_SZ * 2);
  bf16* attn   = (bf16*)alloc((size_t)M_ROWS * DM_SZ * 2);
  float* K1g   = (float*)alloc((size_t)32 * 16 * 64 * 4);
  float* logit = (float*)alloc((size_t)M_ROWS * H_SZ * L_SZ * 4);

  const dim3 blk(256);
  k_prep<<<dim3(1328), blk, 0, stream>>>(x, xb, qw, kw, vw, ow, lw, wqkvT, owT);
  k_gemm_qkvl<<<dim3(N_PAD / 64, M_ROWS / 128), blk, 0, stream>>>(
      xb, wqkvT, qb, kb, vb, lb, Qp, Kpb, KTg, VTg, K1g, logit);
  k_attn<<<dim3((T_SZ / 64) * B_SZ * H_SZ), blk, 0, stream>>>(
      Qp, Kpb, KTg, VTg, K1g, logit, attn);
  k_gemm_out<<<dim3(512), blk, 0, stream>>>(attn, owT, ob, (float*)d_out);
}

// Round 10
// 183.736 us; speedup vs baseline: 1.0419x; 1.0419x over previous
//
#include <hip/hip_runtime.h>
#include <math.h>

typedef __bf16 bf16;
typedef __attribute__((ext_vector_type(4))) __bf16 bf16x4;
typedef __attribute__((ext_vector_type(8))) __bf16 bf16x8;
typedef __attribute__((ext_vector_type(4))) float f32x4;

#define B_SZ 2
#define T_SZ 1024
#define DM_SZ 1024
#define H_SZ 16
#define D_SZ 64
#define L_SZ 12
#define M_ROWS 2048      // B*T
#define N_PAD 3328       // q(1024)+k(1024)+v(1024)+logit(192)+pad(64)

__device__ __forceinline__ f32x4 mfma_16x16x32(bf16x8 a, bf16x8 b, f32x4 c) {
  return __builtin_amdgcn_mfma_f32_16x16x32_bf16(a, b, c, 0, 0, 0);
}

// async global->LDS, 16B/lane; LDS dest = wave-uniform base + lane*16.
__device__ __forceinline__ void gload_lds16(const bf16* g, bf16* l) {
  __builtin_amdgcn_global_load_lds((const __attribute__((address_space(1))) void*)g,
                                   (__attribute__((address_space(3))) void*)l,
                                   16, 0, 0);
}

// ---------------------------------------------------------------------------
// Prep: z=0..3 weight transposes (1024x1024), z=4 lw transpose (1024x192),
// z=5 x fp32->bf16 cast. Grid (16,16,6), block 256.
// ---------------------------------------------------------------------------
__global__ __launch_bounds__(256) void k_prep(
    const float* __restrict__ x, bf16* __restrict__ xb,
    const float* __restrict__ qw, const float* __restrict__ kw,
    const float* __restrict__ vw, const float* __restrict__ ow,
    const float* __restrict__ lw,
    bf16* __restrict__ wqkvT, bf16* __restrict__ owT) {
  const int z = blockIdx.z;
  const int t = threadIdx.x;
  if (z == 5) {  // cast 2048x1024 fp32 -> bf16, 8192 els per block
    const size_t base = ((size_t)blockIdx.y * 16 + blockIdx.x) * 8192 + t * 32;
#pragma unroll
    for (int u = 0; u < 4; ++u) {
      const float* p = x + base + u * 8;
      f32x4 a = *(const f32x4*)p;
      f32x4 b = *(const f32x4*)(p + 4);
      bf16x8 o;
#pragma unroll
      for (int e = 0; e < 4; ++e) { o[e] = (bf16)a[e]; o[e + 4] = (bf16)b[e]; }
      *(bf16x8*)(xb + base + u * 8) = o;
    }
    return;
  }
  __shared__ __align__(16) bf16 tile[64][66];
  const float* in; bf16* out; int C = 1024;
  if (z == 0)      { in = qw; out = wqkvT; }
  else if (z == 1) { in = kw; out = wqkvT + (size_t)1024 * DM_SZ; }
  else if (z == 2) { in = vw; out = wqkvT + (size_t)2048 * DM_SZ; }
  else if (z == 3) { in = ow; out = owT; }
  else             { in = lw; out = wqkvT + (size_t)3072 * DM_SZ; C = 192;
                     if (blockIdx.x >= 3) return; }
  const int tc = blockIdx.x * 64;
  const int tr = blockIdx.y * 64;
  const int r = t >> 2;
  const int c4 = (t & 3) << 4;
  const float* src = in + (size_t)(tr + r) * C + tc + c4;
  f32x4 f0 = *(const f32x4*)(src);
  f32x4 f1 = *(const f32x4*)(src + 4);
  f32x4 f2 = *(const f32x4*)(src + 8);
  f32x4 f3 = *(const f32x4*)(src + 12);
#pragma unroll
  for (int e = 0; e < 4; ++e) {
    tile[r][c4 + e]      = (bf16)f0[e];
    tile[r][c4 + 4 + e]  = (bf16)f1[e];
    tile[r][c4 + 8 + e]  = (bf16)f2[e];
    tile[r][c4 + 12 + e] = (bf16)f3[e];
  }
  __syncthreads();
  bf16x8 w0, w1;
#pragma unroll
  for (int e = 0; e < 8; ++e) { w0[e] = tile[c4 + e][r]; w1[e] = tile[c4 + 8 + e][r]; }
  bf16* dst = out + (size_t)(tc + r) * DM_SZ + tr + c4;
  *(bf16x8*)(dst) = w0;
  *(bf16x8*)(dst + 8) = w1;
}

// ---------------------------------------------------------------------------
// Fused QKVL GEMM: xb(2048x1024) x wqkvT(3328x1024) -> Qp/Kp (phi, bf16),
// VTg (plain, transposed in epilogue), logit (f32, raw). Tile 128x128, BK=64.
// ---------------------------------------------------------------------------
__global__ __launch_bounds__(256) void k_gemm_qkvl(
    const bf16* __restrict__ A, const bf16* __restrict__ Wt,
    const float* __restrict__ qb, const float* __restrict__ kb,
    const float* __restrict__ vb, const float* __restrict__ lb,
    bf16* __restrict__ Qp, bf16* __restrict__ Kp,
    bf16* __restrict__ VTg, float* __restrict__ logit) {
  __shared__ __align__(16) char smem[34816];  // As|Bs (32KB) / Trt (34KB)
  bf16* As = (bf16*)smem;
  bf16* Bs = As + 8192;
  const int nb = blockIdx.x * 128;
  const int mb = blockIdx.y * 128;
  const int t = threadIdx.x;
  const int wv = t >> 6;
  const int lane = t & 63;
  const int l16 = lane & 15;
  const int quad = lane >> 4;
  const int wm = (wv & 1) * 64;
  const int wn = (wv >> 1) * 64;

  const int trow = t >> 3;        // 0..31
  const int tcol = (t & 7) * 8;

  const f32x4 zero4 = {0.f, 0.f, 0.f, 0.f};
  f32x4 acc[4][4];
#pragma unroll
  for (int i = 0; i < 4; ++i)
#pragma unroll
    for (int j = 0; j < 4; ++j) acc[i][j] = zero4;

  const bf16* ag = A + (size_t)(mb + trow) * DM_SZ + tcol;
  const bf16* bg = Wt + (size_t)(nb + trow) * DM_SZ + tcol;

  for (int k0 = 0; k0 < DM_SZ; k0 += 64) {
    __syncthreads();
#pragma unroll
    for (int i = 0; i < 4; ++i)
      gload_lds16(ag + (size_t)i * 32 * DM_SZ + k0, As + i * 2048 + t * 8);
#pragma unroll
    for (int i = 0; i < 4; ++i)
      gload_lds16(bg + (size_t)i * 32 * DM_SZ + k0, Bs + i * 2048 + t * 8);
    __syncthreads();
#pragma unroll
    for (int ks = 0; ks < 2; ++ks) {
      bf16x8 af[4];
#pragma unroll
      for (int mi = 0; mi < 4; ++mi)
        af[mi] = *(const bf16x8*)(As + (wm + mi * 16 + l16) * 64 + ks * 32 + quad * 8);
#pragma unroll
      for (int ni = 0; ni < 4; ++ni) {
        bf16x8 bfr = *(const bf16x8*)(Bs + (wn + ni * 16 + l16) * 64 + ks * 32 + quad * 8);
#pragma unroll
        for (int mi = 0; mi < 4; ++mi)
          acc[mi][ni] = mfma_16x16x32(af[mi], bfr, acc[mi][ni]);
      }
    }
  }

  const int seg = nb >> 10;  // 0=q 1=k 2=v 3=logit
  if (seg < 2) {
    const float* bias = seg == 0 ? qb : kb;
    bf16* outp = seg == 0 ? Qp : Kp;
    const int c0 = (nb & 1023) + wn;
#pragma unroll
    for (int ni = 0; ni < 4; ++ni) {
      const int col = c0 + ni * 16 + l16;
      const float bv = bias[col];
#pragma unroll
      for (int mi = 0; mi < 4; ++mi) {
#pragma unroll
        for (int r = 0; r < 4; ++r) {
          const int row = mb + wm + mi * 16 + quad * 4 + r;
          float v = acc[mi][ni][r] + bv;
          v = (v > 0.f) ? (v + 1.f) : __expf(v);
          outp[(size_t)row * DM_SZ + col] = (bf16)v;
        }
      }
    }
  } else if (seg == 2) {
    // V: bias, transpose via LDS (stride 136), store VTg[b*1024+d][t]
    bf16* Trt = (bf16*)smem;
    const int cb = nb - 2048;
    __syncthreads();  // K-loop LDS frag reads complete before overwrite
#pragma unroll
    for (int ni = 0; ni < 4; ++ni) {
      const int nloc = wn + ni * 16 + l16;
      const float bv = vb[cb + nloc];
#pragma unroll
      for (int mi = 0; mi < 4; ++mi) {
        const int mloc = wm + mi * 16 + quad * 4;
        bf16x4 pk;
#pragma unroll
        for (int r = 0; r < 4; ++r) pk[r] = (bf16)(acc[mi][ni][r] + bv);
        *(bf16x4*)&Trt[nloc * 136 + mloc] = pk;
      }
    }
    __syncthreads();
    const int dn = t >> 1, ch = t & 1;
    const int bq = mb >> 10;
    const int m0g = mb & 1023;
    bf16* dst = VTg + ((size_t)(bq * 1024 + cb + dn)) * T_SZ + m0g + ch * 64;
    const bf16* srcl = Trt + dn * 136 + ch * 64;
#pragma unroll
    for (int e = 0; e < 8; ++e)
      *(bf16x8*)(dst + e * 8) = *(const bf16x8*)(srcl + e * 8);
  } else {
    const int lc0 = (nb - 3072) + wn;
#pragma unroll
    for (int ni = 0; ni < 4; ++ni) {
      const int lcol = lc0 + ni * 16 + l16;
      if (lcol < H_SZ * L_SZ) {
        const float bv = lb[lcol];
#pragma unroll
        for (int mi = 0; mi < 4; ++mi) {
#pragma unroll
          for (int r = 0; r < 4; ++r) {
            const int row = mb + wm + mi * 16 + quad * 4 + r;
            logit[(size_t)row * (H_SZ * L_SZ) + lcol] = acc[mi][ni][r] + bv;
          }
        }
      }
    }
  }
}

// ---------------------------------------------------------------------------
// Fenwick weighted causal linear attention + fused softmax-12.
// Off-diagonal tiles (jt<it): level constant per row — lvl=6+fls(it^jt)
// (row 63: 6+fls((it+1)^jt)); diagonal exact per element.
// ---------------------------------------------------------------------------
__global__ __launch_bounds__(256) void k_attn(const bf16* __restrict__ Qp,
                                              const bf16* __restrict__ Kp,
                                              const bf16* __restrict__ VTg,
                                              const float* __restrict__ Lg,
                                              bf16* __restrict__ O) {
  __shared__ __align__(16) bf16 Ks[64][80];
  __shared__ __align__(16) bf16 VTs[64][80];
  __shared__ __align__(16) bf16 Pl[4][16][80];
  __shared__ float Ws[64 * L_SZ];

  const int idx = blockIdx.x;
  const int s = idx >> 5;
  const int bh = idx & 31;
  const int it = (s < 8) ? (15 - s) : (s - 8);  // heavy-first balance
  const int b = bh >> 4;
  const int h = bh & 15;
  const int i0 = it * 64;
  const int t = threadIdx.x;
  const int wv = t >> 6;
  const int lane = t & 63;
  const int l16 = lane & 15;
  const int quad = lane >> 4;
  const int m0 = wv * 16;

  const size_t base_bt = (size_t)b * T_SZ;

  const bf16* qptr = Qp + (base_bt + i0 + m0 + l16) * DM_SZ + h * 64 + quad * 8;
  const bf16x8 aq0 = *(const bf16x8*)(qptr);
  const bf16x8 aq1 = *(const bf16x8*)(qptr + 32);

  if (t < 64) {  // fused softmax for this block's 64 query rows
    const float* lp = Lg + (base_bt + i0 + t) * (H_SZ * L_SZ) + h * L_SZ;
    float v[L_SZ];
    float m = -1e30f;
#pragma unroll
    for (int l = 0; l < L_SZ; ++l) { v[l] = lp[l]; m = fmaxf(m, v[l]); }
    float sum = 0.f;
#pragma unroll
    for (int l = 0; l < L_SZ; ++l) { v[l] = __expf(v[l] - m); sum += v[l]; }
    const float inv = 1.f / sum;
#pragma unroll
    for (int l = 0; l < L_SZ; ++l) Ws[t * L_SZ + l] = v[l] * inv;
  }

  const f32x4 zero4 = {0.f, 0.f, 0.f, 0.f};
  f32x4 accn[4];
#pragma unroll
  for (int tn = 0; tn < 4; ++tn) accn[tn] = zero4;
  float den[4] = {0.f, 0.f, 0.f, 0.f};

  const int sr = t >> 2;
  const int sc = (t & 3) << 4;
  const int il_base = m0 + quad * 4;

  const bf16* vtrow = VTg + ((size_t)bh * 64 + sr) * T_SZ;

  for (int jt = 0; jt <= it; ++jt) {
    const int j0 = jt * 64;
    const bf16* kpg = Kp + (base_bt + j0 + sr) * DM_SZ + h * 64 + sc;
    bf16x8 k0v = *(const bf16x8*)(kpg);
    bf16x8 k1v = *(const bf16x8*)(kpg + 8);
    const bf16* vpg = vtrow + j0 + sc;
    bf16x8 v0v = *(const bf16x8*)(vpg);
    bf16x8 v1v = *(const bf16x8*)(vpg + 8);
    __syncthreads();
    *(bf16x8*)&Ks[sr][sc] = k0v;
    *(bf16x8*)&Ks[sr][sc + 8] = k1v;
    *(bf16x8*)&VTs[sr][sc] = v0v;
    *(bf16x8*)&VTs[sr][sc + 8] = v1v;
    __syncthreads();

    // S = Qp * Kp^T (16 x 64 per wave)
    f32x4 sacc[4];
#pragma unroll
    for (int tn = 0; tn < 4; ++tn) {
      sacc[tn] = zero4;
      bf16x8 bk0 = *(const bf16x8*)&Ks[tn * 16 + l16][quad * 8];
      bf16x8 bk1 = *(const bf16x8*)&Ks[tn * 16 + l16][32 + quad * 8];
      sacc[tn] = mfma_16x16x32(aq0, bk0, sacc[tn]);
      sacc[tn] = mfma_16x16x32(aq1, bk1, sacc[tn]);
    }

    if (jt < it) {
      // level constant per row across this tile
      const int lvlA = 6 + (31 - __clz((unsigned)(it ^ jt)));
      const int lvlB = 6 + (31 - __clz((unsigned)((it + 1) ^ jt)));
      float wrow[4];
#pragma unroll
      for (int r = 0; r < 4; ++r) {
        const int il = il_base + r;
        wrow[r] = Ws[il * L_SZ + ((il == 63) ? lvlB : lvlA)];
      }
#pragma unroll
      for (int tn = 0; tn < 4; ++tn) {
#pragma unroll
        for (int r = 0; r < 4; ++r) {
          const float p = sacc[tn][r] * wrow[r];
          den[r] += p;
          Pl[wv][quad * 4 + r][(tn * 16 + l16) ^ (quad << 4)] = (bf16)p;
        }
      }
    } else {
      // diagonal tile: exact per-element level + causal mask
#pragma unroll
      for (int tn = 0; tn < 4; ++tn) {
#pragma unroll
        for (int r = 0; r < 4; ++r) {
          const int il = il_base + r;
          const int ig = i0 + il;
          const int jg = j0 + tn * 16 + l16;
          float p = 0.f;
          if (jg <= ig) {
            const int lvl = 31 - __clz((unsigned)((ig + 1) ^ jg));
            p = sacc[tn][r] * Ws[il * L_SZ + lvl];
          }
          den[r] += p;
          Pl[wv][quad * 4 + r][(tn * 16 + l16) ^ (quad << 4)] = (bf16)p;
        }
      }
    }

    // num += P @ V
#pragma unroll
    for (int ks = 0; ks < 2; ++ks) {
      bf16x8 apf = *(const bf16x8*)&Pl[wv][l16][(ks * 32 + quad * 8) ^ ((l16 >> 2) << 4)];
#pragma unroll
      for (int tn = 0; tn < 4; ++tn) {
        bf16x8 bvf = *(const bf16x8*)&VTs[tn * 16 + l16][ks * 32 + quad * 8];
        accn[tn] = mfma_16x16x32(apf, bvf, accn[tn]);
      }
    }
  }

#pragma unroll
  for (int r = 0; r < 4; ++r) {
    float d = den[r];
    d += __shfl_xor(d, 1, 64);
    d += __shfl_xor(d, 2, 64);
    d += __shfl_xor(d, 4, 64);
    d += __shfl_xor(d, 8, 64);
    den[r] = fmaxf(d, 1e-6f);
  }

#pragma unroll
  for (int tn = 0; tn < 4; ++tn) {
#pragma unroll
    for (int r = 0; r < 4; ++r) {
      const int il = il_base + r;
      O[(base_bt + i0 + il) * DM_SZ + h * 64 + tn * 16 + l16] =
          (bf16)(accn[tn][r] / den[r]);
    }
  }
}

// ---------------------------------------------------------------------------
// Output GEMM: attn(2048x1024) x owT(1024x1024) + ob -> f32 out.
// Tile 64x64, grid (16,32)=512 blocks, global_load_lds staging.
// ---------------------------------------------------------------------------
__global__ __launch_bounds__(256) void k_gemm_out(const bf16* __restrict__ A,
                                                  const bf16* __restrict__ Wt,
                                                  const float* __restrict__ ob,
                                                  float* __restrict__ out) {
  __shared__ __align__(16) bf16 As[64 * 64];
  __shared__ __align__(16) bf16 Bs[64 * 64];
  const int nb = blockIdx.x * 64;
  const int mb = blockIdx.y * 64;
  const int t = threadIdx.x;
  const int wv = t >> 6;
  const int lane = t & 63;
  const int l16 = lane & 15;
  const int quad = lane >> 4;
  const int wm = wv * 16;

  const int trow = t >> 3;
  const int tcol = (t & 7) * 8;

  const f32x4 zero4 = {0.f, 0.f, 0.f, 0.f};
  f32x4 acc[4];
#pragma unroll
  for (int j = 0; j < 4; ++j) acc[j] = zero4;

  const bf16* ag = A + (size_t)(mb + trow) * DM_SZ + tcol;
  const bf16* bg = Wt + (size_t)(nb + trow) * DM_SZ + tcol;

  for (int k0 = 0; k0 < DM_SZ; k0 += 64) {
    __syncthreads();
    gload_lds16(ag + k0, As + t * 8);
    gload_lds16(ag + (size_t)32 * DM_SZ + k0, As + 2048 + t * 8);
    gload_lds16(bg + k0, Bs + t * 8);
    gload_lds16(bg + (size_t)32 * DM_SZ + k0, Bs + 2048 + t * 8);
    __syncthreads();
#pragma unroll
    for (int ks = 0; ks < 2; ++ks) {
      bf16x8 af = *(const bf16x8*)(As + (wm + l16) * 64 + ks * 32 + quad * 8);
#pragma unroll
      for (int ni = 0; ni < 4; ++ni) {
        bf16x8 bfr = *(const bf16x8*)(Bs + (ni * 16 + l16) * 64 + ks * 32 + quad * 8);
        acc[ni] = mfma_16x16x32(af, bfr, acc[ni]);
      }
    }
  }
#pragma unroll
  for (int ni = 0; ni < 4; ++ni) {
    const int col = nb + ni * 16 + l16;
    const float bv = ob[col];
#pragma unroll
    for (int r = 0; r < 4; ++r) {
      const int row = mb + wm + quad * 4 + r;
      out[(size_t)row * DM_SZ + col] = acc[ni][r] + bv;
    }
  }
}

// ---------------------------------------------------------------------------
extern "C" void kernel_launch(void* const* d_in, const int* in_sizes, int n_in,
                              void* d_out, int out_size, void* d_ws, size_t ws_size,
                              hipStream_t stream) {
  (void)in_sizes; (void)n_in; (void)out_size; (void)ws_size;
  const float* x  = (const float*)d_in[0];
  const float* qw = (const float*)d_in[1];
  const float* qb = (const float*)d_in[2];
  const float* kw = (const float*)d_in[3];
  const float* kb = (const float*)d_in[4];
  const float* vw = (const float*)d_in[5];
  const float* vb = (const float*)d_in[6];
  const float* lw = (const float*)d_in[7];
  const float* lb = (const float*)d_in[8];
  const float* ow = (const float*)d_in[9];
  const float* ob = (const float*)d_in[10];
  // d_in[11] = level_masks: unused — lvl(i,j) = 31 - clz((i+1)^j).

  char* ws = (char*)d_ws;
  size_t off = 0;
  auto alloc = [&](size_t bytes) -> char* {
    char* p = ws + off;
    off += (bytes + 255) & ~(size_t)255;
    return p;
  };
  bf16* xb     = (bf16*)alloc((size_t)M_ROWS * DM_SZ * 2);
  bf16* wqkvT  = (bf16*)alloc((size_t)N_PAD * DM_SZ * 2);  // rows 3264..3327 garbage (harmless)
  bf16* owT    = (bf16*)alloc((size_t)DM_SZ * DM_SZ * 2);
  bf16* Qp     = (bf16*)alloc((size_t)M_ROWS * DM_SZ * 2);
  bf16* Kpb    = (bf16*)alloc((size_t)M_ROWS * DM_SZ * 2);
  bf16* VTg    = (bf16*)alloc((size_t)M_ROWS * DM_SZ * 2);
  bf16* attn   = (bf16*)alloc((size_t)M_ROWS * DM_SZ * 2);
  float* logit = (float*)alloc((size_t)M_ROWS * H_SZ * L_SZ * 4);

  const dim3 blk(256);
  k_prep<<<dim3(16, 16, 6), blk, 0, stream>>>(x, xb, qw, kw, vw, ow, lw, wqkvT, owT);
  k_gemm_qkvl<<<dim3(N_PAD / 128, M_ROWS / 128), blk, 0, stream>>>(
      xb, wqkvT, qb, kb, vb, lb, Qp, Kpb, VTg, logit);
  k_attn<<<dim3((T_SZ / 64) * B_SZ * H_SZ), blk, 0, stream>>>(Qp, Kpb, VTg, logit, attn);
  k_gemm_out<<<dim3(DM_SZ / 64, M_ROWS / 64), blk, 0, stream>>>(attn, owT, ob, (float*)d_out);
}